// Round 1
// 166.316 us; speedup vs baseline: 1.2106x; 1.2106x over previous
//
#include <hip/hip_runtime.h>
#include <hip/hip_bf16.h>

#define BSZ 131072

typedef __bf16 v8bf __attribute__((ext_vector_type(8)));
typedef float f32x4 __attribute__((ext_vector_type(4)));

constexpr int RPB = 64;        // rows per block
constexpr int NTHREADS = 512;  // 8 waves
constexpr int LDA = 264;       // 256 + 8 pad (528B rows, 16B aligned)

// d_ws layout (bf16 element offsets) — fragment-swizzled weights.
// NOTE: for 16x16x32 the A-frag and B-frag lane layouts are transposes of
// each other, so the SAME buffers now serve as the A-operand in the
// swapped (transposed-output) MFMA orientation. prep_weights unchanged.
constexpr int OFF_B2T = 0;        // Vw2[n][k]   (256x256) NT=16
constexpr int OFF_U2T = 65536;    // Uw2[n][k]   (256x256) NT=16
constexpr int OFF_B2  = 131072;   // Vw2[k][n]   (256x256) NT=16
constexpr int OFF_B3T = 196608;   // Vw3[n][k]   (256x64)  NT=4
constexpr int OFF_B3  = 212992;   // Vw3[k][n]   (64x256)  NT=16
constexpr int OFF_U3  = 229376;   // Uw3[k], cols 1..15 zero (256x16) NT=1
constexpr int OFF_GV  = 233472;   // Vw1[k][n] n<4 else 0  (256x16) NT=1
constexpr int OFF_LV1 = 237568;   // Vw1[n][k] k<4 else 0  (32x256)  NT=16
constexpr int OFF_LU1 = 245760;   // Uw1[n][k] k<4 else 0  (32x256)  NT=16
constexpr int WS_ELEMS = 253952;

// rcp-based tanh: no IEEE div sequence (~9 VALU saved per call).
// exact at +-inf, no NaN; rcp err ~1ulp << bf16 storage rounding.
__device__ __forceinline__ float tanhf_fast(float x){
  float e = __expf(2.0f * x);
  return 1.0f - 2.0f * __builtin_amdgcn_rcpf(e + 1.0f);
}

// cheap bf16 convert (kept for prep_weights + xa build)
__device__ __forceinline__ __bf16 f2bf(float f){
  unsigned u = __builtin_bit_cast(unsigned, f);
  u += 0x8000u;
  unsigned short h = (unsigned short)(u >> 16);
  return __builtin_bit_cast(__bf16, h);
}

// pack 2 f32 -> 2 bf16 in one instr (RNE)
__device__ __forceinline__ unsigned pk2bf(float lo, float hi){
  unsigned r;
  asm("v_cvt_pk_bf16_f32 %0, %1, %2" : "=v"(r) : "v"(lo), "v"(hi));
  return r;
}
__device__ __forceinline__ float bflo(unsigned u){ return __builtin_bit_cast(float, u << 16); }
__device__ __forceinline__ float bfhi(unsigned u){ return __builtin_bit_cast(float, u & 0xffff0000u); }

// ---- weight pre-swizzle: one thread per bf16 element of ws ----
// Fragment storage: frag f=(kstep*NT+ntile); lane l holds 8 contiguous bf16:
//   element j of lane l = B[kstep*32 + (l>>4)*8 + j][ntile*16 + (l&15)]
__global__ void prep_weights(const float* __restrict__ Vw2,
                             const float* __restrict__ Uw2,
                             const float* __restrict__ Vw3,
                             const float* __restrict__ Vw1,
                             const float* __restrict__ Uw1,
                             const float* __restrict__ Uw3,
                             __bf16* __restrict__ ws){
  int e = blockIdx.x * 256 + threadIdx.x;
  if (e >= WS_ELEMS) return;
  int idx, NT, base, mode; const float* W;
  if      (e <  65536){ idx = e;          W = Vw2; mode = 0; NT = 16; base = OFF_B2T; }
  else if (e < 131072){ idx = e - 65536;  W = Uw2; mode = 0; NT = 16; base = OFF_U2T; }
  else if (e < 196608){ idx = e - 131072; W = Vw2; mode = 1; NT = 16; base = OFF_B2;  }
  else if (e < 212992){ idx = e - 196608; W = Vw3; mode = 0; NT = 4;  base = OFF_B3T; }
  else if (e < 229376){ idx = e - 212992; W = Vw3; mode = 1; NT = 16; base = OFF_B3;  }
  else if (e < 233472){ idx = e - 229376; W = Uw3; mode = 2; NT = 1;  base = OFF_U3;  }
  else if (e < 237568){ idx = e - 233472; W = Vw1; mode = 3; NT = 1;  base = OFF_GV;  }
  else if (e < 245760){ idx = e - 237568; W = Vw1; mode = 4; NT = 16; base = OFF_LV1; }
  else                { idx = e - 245760; W = Uw1; mode = 4; NT = 16; base = OFF_LU1; }
  int j = idx & 7, l = (idx >> 3) & 63, f = idx >> 9;
  int nt = f % NT, ks = f / NT;
  int k = ks * 32 + (l >> 4) * 8 + j;
  int n = nt * 16 + (l & 15);
  float v;
  if      (mode == 0) v = W[n * 256 + k];
  else if (mode == 1) v = W[k * 256 + n];
  else if (mode == 2) v = (n == 0) ? W[k] : 0.0f;
  else if (mode == 3) v = (n < 4)  ? W[k * 4 + n] : 0.0f;
  else                v = (k < 4)  ? W[n * 4 + k] : 0.0f;
  ws[base + idx] = f2bf(v);
}

__global__ __launch_bounds__(NTHREADS, 4) void fused_clf(
    const float* __restrict__ x,
    const float* __restrict__ Vb1, const float* __restrict__ Vb2,
    const float* __restrict__ Vb3,
    const float* __restrict__ Ub1, const float* __restrict__ Ub2,
    const float* __restrict__ Ub3,
    const __bf16* __restrict__ ws,
    float* __restrict__ out)
{
  __shared__ alignas(16) __bf16 b1[RPB][LDA];   // u2 | a1 -> s2'
  __shared__ alignas(16) __bf16 b2[RPB][LDA];   // u1 | a2 -> t2'
  __shared__ union alignas(16) S3 {             // b3 live z3..t3; r4 for reduces
    __bf16 b3[RPB][72];                         // a3' = a3*(1-a3^2)
    float  r4[8][RPB][4];                       // per-wave MFMA reduction partials
  } s3;
  __shared__ alignas(16) float red[RPB][4];
  __shared__ float utile[RPB];

  const int tid  = threadIdx.x;
  const int lane = tid & 63;
  const int wave = tid >> 6;       // 0..7
  const int quad = lane >> 4;
  const int l16  = lane & 15;
  const int row0 = blockIdx.x * RPB;

  // ---- x fragments (K=4 zero-padded to 32). Used as the B-operand now;
  // B-frag layout == old A-frag layout, so the build is unchanged. ----
  v8bf xa[4];
  #pragma unroll
  for (int m = 0; m < 4; m++){
    v8bf z;
    #pragma unroll
    for (int j = 0; j < 8; j++) z[j] = (__bf16)0.0f;
    if (quad == 0){
      float4 xv = ((const float4*)x)[row0 + m*16 + l16];
      z[0] = f2bf(xv.x); z[1] = f2bf(xv.y); z[2] = f2bf(xv.z); z[3] = f2bf(xv.w);
    }
    xa[m] = z;
  }

  // Swapped-operand MFMA: acc = mfma(Wfrag, ActFrag) computes C^T, so
  // lane holds features f0..f0+3 (f0 = ntbase + quad*4) of batch row
  // m*16+l16 -> 4 consecutive bf16 -> single ds_write_b64 (conflict-free:
  // bank starts 4*l16+2*quad tile all 32 banks exactly).

  // ---- layer-1 via MFMA (single K-step) ----
  auto layer1m = [&](const __bf16* __restrict__ Bw, const float* __restrict__ bv,
                     __bf16 (*dst)[LDA]){
    const v8bf* B = (const v8bf*)Bw;
    v8bf bf0 = B[(wave*2 + 0)*64 + lane];
    v8bf bf1 = B[(wave*2 + 1)*64 + lane];
    f32x4 acc[4][2];
    #pragma unroll
    for (int m = 0; m < 4; m++){ f32x4 z={0.f,0.f,0.f,0.f}; acc[m][0]=z; acc[m][1]=z; }
    #pragma unroll
    for (int m = 0; m < 4; m++){
      acc[m][0] = __builtin_amdgcn_mfma_f32_16x16x32_bf16(bf0, xa[m], acc[m][0], 0,0,0);
      acc[m][1] = __builtin_amdgcn_mfma_f32_16x16x32_bf16(bf1, xa[m], acc[m][1], 0,0,0);
    }
    #pragma unroll
    for (int nt = 0; nt < 2; nt++){
      const int f0 = (wave*2 + nt)*16 + quad*4;
      f32x4 bvv = ((const f32x4*)bv)[f0 >> 2];
      #pragma unroll
      for (int m = 0; m < 4; m++){
        const int brow = m*16 + l16;
        uint2 pk;
        pk.x = pk2bf(tanhf_fast(acc[m][nt][0] + bvv[0]),
                     tanhf_fast(acc[m][nt][1] + bvv[1]));
        pk.y = pk2bf(tanhf_fast(acc[m][nt][2] + bvv[2]),
                     tanhf_fast(acc[m][nt][3] + bvv[3]));
        *(uint2*)&dst[brow][f0] = pk;
      }
    }
  };

  // ---- (64x256)x(256x256): wave = 2 n-tiles, all 4 m-tiles ----
  auto gemm256 = [&](const __bf16 (*A)[LDA], const __bf16* __restrict__ Bw,
                     const float* __restrict__ bias, __bf16 (*dst)[LDA], int epi){
    f32x4 acc[4][2];
    #pragma unroll
    for (int m = 0; m < 4; m++){ f32x4 z={0.f,0.f,0.f,0.f}; acc[m][0]=z; acc[m][1]=z; }
    const v8bf* B = (const v8bf*)Bw;
    #pragma unroll
    for (int kk = 0; kk < 8; kk++){
      v8bf a[4];
      #pragma unroll
      for (int m = 0; m < 4; m++)
        a[m] = *(const v8bf*)&A[m*16 + l16][kk*32 + quad*8];
      #pragma unroll
      for (int nt = 0; nt < 2; nt++){
        v8bf bf = B[(kk*16 + wave*2 + nt)*64 + lane];
        #pragma unroll
        for (int m = 0; m < 4; m++)
          acc[m][nt] = __builtin_amdgcn_mfma_f32_16x16x32_bf16(bf, a[m], acc[m][nt], 0,0,0);
      }
    }
    #pragma unroll
    for (int nt = 0; nt < 2; nt++){
      const int f0 = (wave*2 + nt)*16 + quad*4;
      f32x4 bvv = {0.f,0.f,0.f,0.f};
      if (epi == 0) bvv = ((const f32x4*)bias)[f0 >> 2];
      #pragma unroll
      for (int m = 0; m < 4; m++){
        const int brow = m*16 + l16;
        uint2 pk;
        if (epi == 0){
          pk.x = pk2bf(tanhf_fast(acc[m][nt][0] + bvv[0]),
                       tanhf_fast(acc[m][nt][1] + bvv[1]));
          pk.y = pk2bf(tanhf_fast(acc[m][nt][2] + bvv[2]),
                       tanhf_fast(acc[m][nt][3] + bvv[3]));
        } else {
          uint2 old = *(const uint2*)&dst[brow][f0];
          float a0 = bflo(old.x), a1 = bfhi(old.x);
          float c0 = bflo(old.y), c1 = bfhi(old.y);
          pk.x = pk2bf(acc[m][nt][0] * (1.0f - a0*a0),
                       acc[m][nt][1] * (1.0f - a1*a1));
          pk.y = pk2bf(acc[m][nt][2] * (1.0f - c0*c0),
                       acc[m][nt][3] * (1.0f - c1*c1));
        }
        *(uint2*)&dst[brow][f0] = pk;
      }
    }
  };

  // ---- N=16 MFMA reduction partial: K split across 8 waves ----
  // Output rows are features now: quad==0 lanes hold features 0..3 of
  // batch m*16+l16 -> b128 store of the f32x4 for ncols=4.
  auto mfma_reduce = [&](const __bf16 (*A)[LDA], const __bf16* __restrict__ Bw,
                         int ncols){
    f32x4 acc[4];
    #pragma unroll
    for (int m = 0; m < 4; m++){ f32x4 z={0.f,0.f,0.f,0.f}; acc[m]=z; }
    const v8bf* B = (const v8bf*)Bw;
    v8bf bf = B[wave*64 + lane];           // frag ks = wave (NT=1)
    #pragma unroll
    for (int m = 0; m < 4; m++){
      v8bf a = *(const v8bf*)&A[m*16 + l16][wave*32 + quad*8];
      acc[m] = __builtin_amdgcn_mfma_f32_16x16x32_bf16(bf, a, acc[m], 0,0,0);
    }
    if (quad == 0){
      if (ncols == 4){
        #pragma unroll
        for (int m = 0; m < 4; m++)
          *(f32x4*)&s3.r4[wave][m*16 + l16][0] = acc[m];
      } else {
        #pragma unroll
        for (int m = 0; m < 4; m++)
          s3.r4[wave][m*16 + l16][0] = acc[m][0];
      }
    }
  };

  // ================= U network =================
  layer1m(ws + OFF_LU1, Ub1, b2);          // u1 -> b2
  __syncthreads();
  gemm256(b2, ws + OFF_U2T, Ub2, b1, 0);   // u2 -> b1
  __syncthreads();
  mfma_reduce(b1, ws + OFF_U3, 1);         // u2 . Uw3 partials -> r4
  __syncthreads();
  if (tid < RPB){                          // wave 0: finish u
    float z = Ub3[0];
    #pragma unroll
    for (int w = 0; w < 8; w++) z += s3.r4[w][tid][0];
    float u = tanhf_fast(z) * 20.0f;
    utile[tid] = u;
    out[row0 + tid] = u;
  }
  // ================= V network =================
  layer1m(ws + OFF_LV1, Vb1, b1);          // a1 -> b1 (u2 consumed)
  __syncthreads();
  gemm256(b1, ws + OFF_B2T, Vb2, b2, 0);   // a2 -> b2
  __syncthreads();

  // z3: a2 @ Vw3^T -> a3. wave = (m-pair, n-tile of 16 features).
  // V row-partials: sum t^2 over the lane's 4 features, then butterfly
  // over quad (xor 16, 32). Store a3' = a3*(1-a3^2) packed b64.
  {
    const int mp = wave >> 2;     // 0..1
    const int nt = wave & 3;      // 0..3
    f32x4 acc[2];
    { f32x4 z={0.f,0.f,0.f,0.f}; acc[0]=z; acc[1]=z; }
    const v8bf* B = (const v8bf*)(ws + OFF_B3T);
    #pragma unroll
    for (int kk = 0; kk < 8; kk++){
      v8bf bf = B[(kk*4 + nt)*64 + lane];
      #pragma unroll
      for (int m2 = 0; m2 < 2; m2++){
        v8bf a = *(const v8bf*)&b2[(mp*2 + m2)*16 + l16][kk*32 + quad*8];
        acc[m2] = __builtin_amdgcn_mfma_f32_16x16x32_bf16(bf, a, acc[m2], 0,0,0);
      }
    }
    const int f0 = nt*16 + quad*4;
    f32x4 bvv = ((const f32x4*)Vb3)[f0 >> 2];
    #pragma unroll
    for (int m2 = 0; m2 < 2; m2++){
      const int brow = (mp*2 + m2)*16 + l16;
      float t0 = tanhf_fast(acc[m2][0] + bvv[0]);
      float t1 = tanhf_fast(acc[m2][1] + bvv[1]);
      float t2 = tanhf_fast(acc[m2][2] + bvv[2]);
      float t3 = tanhf_fast(acc[m2][3] + bvv[3]);
      float s0 = t0*t0, s1 = t1*t1, s2 = t2*t2, s3q = t3*t3;
      float sq = (s0 + s1) + (s2 + s3q);
      sq += __shfl_xor(sq, 16);
      sq += __shfl_xor(sq, 32);
      if (quad == 0) red[brow][nt] = sq;
      uint2 pk;
      pk.x = pk2bf(t0*(1.0f - s0), t1*(1.0f - s1));
      pk.y = pk2bf(t2*(1.0f - s2), t3*(1.0f - s3q));
      *(uint2*)&s3.b3[brow][f0] = pk;
    }
  }
  __syncthreads();

  // t3 = a3' @ Vw3 ; epilogue t2' = t3*(1-a2^2) in place into b2. Also emit V.
  {
    f32x4 acc[4][2];
    #pragma unroll
    for (int m = 0; m < 4; m++){ f32x4 z={0.f,0.f,0.f,0.f}; acc[m][0]=z; acc[m][1]=z; }
    const v8bf* B = (const v8bf*)(ws + OFF_B3);
    #pragma unroll
    for (int kk = 0; kk < 2; kk++){
      v8bf a[4];
      #pragma unroll
      for (int m = 0; m < 4; m++)
        a[m] = *(const v8bf*)&s3.b3[m*16 + l16][kk*32 + quad*8];
      #pragma unroll
      for (int nt = 0; nt < 2; nt++){
        v8bf bf = B[(kk*16 + wave*2 + nt)*64 + lane];
        #pragma unroll
        for (int m = 0; m < 4; m++)
          acc[m][nt] = __builtin_amdgcn_mfma_f32_16x16x32_bf16(bf, a[m], acc[m][nt], 0,0,0);
      }
    }
    #pragma unroll
    for (int nt = 0; nt < 2; nt++){
      const int f0 = (wave*2 + nt)*16 + quad*4;
      #pragma unroll
      for (int m = 0; m < 4; m++){
        const int brow = m*16 + l16;
        uint2 old = *(const uint2*)&b2[brow][f0];
        float a0 = bflo(old.x), a1 = bfhi(old.x);
        float c0 = bflo(old.y), c1 = bfhi(old.y);
        uint2 pk;
        pk.x = pk2bf(acc[m][nt][0] * (1.0f - a0*a0),
                     acc[m][nt][1] * (1.0f - a1*a1));
        pk.y = pk2bf(acc[m][nt][2] * (1.0f - c0*c0),
                     acc[m][nt][3] * (1.0f - c1*c1));
        *(uint2*)&b2[brow][f0] = pk;
      }
    }
    if (tid < RPB)
      out[BSZ + row0 + tid] = 0.5f * (red[tid][0] + red[tid][1] + red[tid][2] + red[tid][3]);
  }
  __syncthreads();

  gemm256(b2, ws + OFF_B2, nullptr, b1, 1);  // s2' = (t2'@Vw2)*(1-a1^2) -> b1
  __syncthreads();
  mfma_reduce(b1, ws + OFF_GV, 4);           // grad_V partials -> r4 (b3 dead)
  __syncthreads();
  if (tid < 256){
    int b = tid >> 2, k2 = tid & 3;
    float s = 0.f;
    #pragma unroll
    for (int w = 0; w < 8; w++) s += s3.r4[w][b][k2];
    red[b][k2] = s;
  }
  __syncthreads();

  // dynamics + Vdot (rcp instead of IEEE div; native sincos)
  if (tid < RPB){
    float4 xv = ((const float4*)x)[row0 + tid];
    float th = xv.y, vv = xv.z, om = xv.w;
    float c, s;
    __sincosf(th, &s, &c);
    float rdc  = __builtin_amdgcn_rcpf(c - 24.7f);
    float rdc2 = __builtin_amdgcn_rcpf(c*c - 24.7f);
    float f2v = (c*(9.8f*s + 11.5f*vv) + 68.4f*vv - 1.2f*om*om*s) * rdc;
    float f3v = (-58.8f*vv*c - 243.5f*vv - s*(208.3f + om*om*c)) * rdc2;
    float g2v = (-1.8f*c - 10.9f) * rdc;
    float g3v = (9.3f*c + 38.6f) * rdc2;
    f32x4 rv = *(const f32x4*)&red[tid][0];
    float Lf = rv[0]*vv + rv[1]*om + rv[2]*f2v + rv[3]*f3v;
    float Lg = rv[2]*g2v + rv[3]*g3v;
    out[2*BSZ + row0 + tid] = Lf + Lg * utile[tid];
  }
}

extern "C" void kernel_launch(void* const* d_in, const int* in_sizes, int n_in,
                              void* d_out, int out_size, void* d_ws, size_t ws_size,
                              hipStream_t stream) {
  const float* x   = (const float*)d_in[0];
  const float* Vw1 = (const float*)d_in[1];
  const float* Vb1 = (const float*)d_in[2];
  const float* Vw2 = (const float*)d_in[3];
  const float* Vb2 = (const float*)d_in[4];
  const float* Vw3 = (const float*)d_in[5];
  const float* Vb3 = (const float*)d_in[6];
  const float* Uw1 = (const float*)d_in[7];
  const float* Ub1 = (const float*)d_in[8];
  const float* Uw2 = (const float*)d_in[9];
  const float* Ub2 = (const float*)d_in[10];
  const float* Uw3 = (const float*)d_in[11];
  const float* Ub3 = (const float*)d_in[12];
  __bf16* ws = (__bf16*)d_ws;
  float* out = (float*)d_out;

  hipLaunchKernelGGL(prep_weights, dim3((WS_ELEMS + 255) / 256), dim3(256), 0, stream,
                     Vw2, Uw2, Vw3, Vw1, Uw1, Uw3, ws);
  hipLaunchKernelGGL(fused_clf, dim3(BSZ / RPB), dim3(NTHREADS), 0, stream,
                     x, Vb1, Vb2, Vb3, Ub1, Ub2, Ub3, ws, out);
}

// Round 2
// 160.838 us; speedup vs baseline: 1.2519x; 1.0341x over previous
//
#include <hip/hip_runtime.h>
#include <hip/hip_bf16.h>

#define BSZ 131072

typedef __bf16 v8bf __attribute__((ext_vector_type(8)));
typedef float f32x4 __attribute__((ext_vector_type(4)));

constexpr int RPB = 64;        // rows per block
constexpr int NTHREADS = 512;  // 8 waves
constexpr int LDA = 264;       // 256 + 8 pad (528B rows, 16B aligned)

// d_ws layout (bf16 element offsets) — fragment-swizzled weights.
constexpr int OFF_B2T = 0;        // Vw2[n][k]   (256x256) NT=16
constexpr int OFF_U2T = 65536;    // Uw2[n][k]   (256x256) NT=16
constexpr int OFF_B2  = 131072;   // Vw2[k][n]   (256x256) NT=16
constexpr int OFF_B3T = 196608;   // Vw3[n][k]   (256x64)  NT=4
constexpr int OFF_B3  = 212992;   // Vw3[k][n]   (64x256)  NT=16
constexpr int OFF_U3  = 229376;   // Uw3[k] (unused by fused_clf now)
constexpr int OFF_GV  = 233472;   // Vw1[k][n] n<4 else 0  (256x16) NT=1
constexpr int OFF_LV1 = 237568;   // Vw1[n][k] k<4 else 0  (32x256)  NT=16
constexpr int OFF_LU1 = 245760;   // Uw1[n][k] k<4 else 0  (32x256)  NT=16
constexpr int WS_ELEMS = 253952;

// 3 VALU + 2 trans: exp2-form tanh. Exact at +-inf, no NaN.
__device__ __forceinline__ float tanhf_fast(float x){
  float e = __builtin_amdgcn_exp2f(x * 2.885390082f);   // exp(2x)
  return __builtin_fmaf(-2.0f, __builtin_amdgcn_rcpf(e + 1.0f), 1.0f);
}

__device__ __forceinline__ __bf16 f2bf(float f){
  unsigned u = __builtin_bit_cast(unsigned, f);
  u += 0x8000u;
  unsigned short h = (unsigned short)(u >> 16);
  return __builtin_bit_cast(__bf16, h);
}

// pack 2 f32 -> 2 bf16 in one instr (RNE)
__device__ __forceinline__ unsigned pk2bf(float lo, float hi){
  unsigned r;
  asm("v_cvt_pk_bf16_f32 %0, %1, %2" : "=v"(r) : "v"(lo), "v"(hi));
  return r;
}
__device__ __forceinline__ float bflo(unsigned u){ return __builtin_bit_cast(float, u << 16); }
__device__ __forceinline__ float bfhi(unsigned u){ return __builtin_bit_cast(float, u & 0xffff0000u); }

// ---- weight pre-swizzle: one thread per bf16 element of ws ----
__global__ void prep_weights(const float* __restrict__ Vw2,
                             const float* __restrict__ Uw2,
                             const float* __restrict__ Vw3,
                             const float* __restrict__ Vw1,
                             const float* __restrict__ Uw1,
                             const float* __restrict__ Uw3,
                             __bf16* __restrict__ ws){
  int e = blockIdx.x * 256 + threadIdx.x;
  if (e >= WS_ELEMS) return;
  int idx, NT, base, mode; const float* W;
  if      (e <  65536){ idx = e;          W = Vw2; mode = 0; NT = 16; base = OFF_B2T; }
  else if (e < 131072){ idx = e - 65536;  W = Uw2; mode = 0; NT = 16; base = OFF_U2T; }
  else if (e < 196608){ idx = e - 131072; W = Vw2; mode = 1; NT = 16; base = OFF_B2;  }
  else if (e < 212992){ idx = e - 196608; W = Vw3; mode = 0; NT = 4;  base = OFF_B3T; }
  else if (e < 229376){ idx = e - 212992; W = Vw3; mode = 1; NT = 16; base = OFF_B3;  }
  else if (e < 233472){ idx = e - 229376; W = Uw3; mode = 2; NT = 1;  base = OFF_U3;  }
  else if (e < 237568){ idx = e - 233472; W = Vw1; mode = 3; NT = 1;  base = OFF_GV;  }
  else if (e < 245760){ idx = e - 237568; W = Vw1; mode = 4; NT = 16; base = OFF_LV1; }
  else                { idx = e - 245760; W = Uw1; mode = 4; NT = 16; base = OFF_LU1; }
  int j = idx & 7, l = (idx >> 3) & 63, f = idx >> 9;
  int nt = f % NT, ks = f / NT;
  int k = ks * 32 + (l >> 4) * 8 + j;
  int n = nt * 16 + (l & 15);
  float v;
  if      (mode == 0) v = W[n * 256 + k];
  else if (mode == 1) v = W[k * 256 + n];
  else if (mode == 2) v = (n == 0) ? W[k] : 0.0f;
  else if (mode == 3) v = (n < 4)  ? W[k * 4 + n] : 0.0f;
  else                v = (k < 4)  ? W[n * 4 + k] : 0.0f;
  ws[base + idx] = f2bf(v);
}

__global__ __launch_bounds__(NTHREADS, 4) void fused_clf(
    const float* __restrict__ x,
    const float* __restrict__ Vb1, const float* __restrict__ Vb2,
    const float* __restrict__ Vb3,
    const float* __restrict__ Ub1, const float* __restrict__ Ub2,
    const float* __restrict__ Ub3, const float* __restrict__ Uw3,
    const __bf16* __restrict__ ws,
    float* __restrict__ out)
{
  __shared__ alignas(16) __bf16 b1[RPB][LDA];   // a1 -> s2'
  __shared__ alignas(16) __bf16 b2[RPB][LDA];   // u1 | a2 -> t2'
  __shared__ union alignas(16) S3 {             // r4 (U3/gradV partials) | b3
    __bf16 b3[RPB][72];                         // a3' = a3*(1-a3^2)
    float  r4[8][RPB][4];                       // per-wave reduction partials
  } s3;
  __shared__ alignas(16) float red[RPB][4];
  __shared__ float utile[RPB];

  const int tid  = threadIdx.x;
  const int lane = tid & 63;
  const int wave = tid >> 6;       // 0..7
  const int quad = lane >> 4;
  const int l16  = lane & 15;
  const int row0 = blockIdx.x * RPB;

  // ---- x fragments (K=4 zero-padded to 32), B-operand of swapped MFMA ----
  v8bf xa[4];
  #pragma unroll
  for (int m = 0; m < 4; m++){
    v8bf z;
    #pragma unroll
    for (int j = 0; j < 8; j++) z[j] = (__bf16)0.0f;
    if (quad == 0){
      float4 xv = ((const float4*)x)[row0 + m*16 + l16];
      z[0] = f2bf(xv.x); z[1] = f2bf(xv.y); z[2] = f2bf(xv.z); z[3] = f2bf(xv.w);
    }
    xa[m] = z;
  }

  // Swapped-operand MFMA: acc = mfma(Wfrag, ActFrag) computes C^T: lane
  // holds features f0..f0+3 (f0 = ntbase + quad*4) of batch row m*16+l16.

  // ---- layer-1 via MFMA (single K-step) ----
  auto layer1m = [&](const __bf16* __restrict__ Bw, const float* __restrict__ bv,
                     __bf16 (*dst)[LDA]){
    const v8bf* B = (const v8bf*)Bw;
    v8bf bf0 = B[(wave*2 + 0)*64 + lane];
    v8bf bf1 = B[(wave*2 + 1)*64 + lane];
    f32x4 acc[4][2];
    #pragma unroll
    for (int m = 0; m < 4; m++){ f32x4 z={0.f,0.f,0.f,0.f}; acc[m][0]=z; acc[m][1]=z; }
    __builtin_amdgcn_s_setprio(1);
    #pragma unroll
    for (int m = 0; m < 4; m++){
      acc[m][0] = __builtin_amdgcn_mfma_f32_16x16x32_bf16(bf0, xa[m], acc[m][0], 0,0,0);
      acc[m][1] = __builtin_amdgcn_mfma_f32_16x16x32_bf16(bf1, xa[m], acc[m][1], 0,0,0);
    }
    __builtin_amdgcn_s_setprio(0);
    #pragma unroll
    for (int nt = 0; nt < 2; nt++){
      const int f0 = (wave*2 + nt)*16 + quad*4;
      f32x4 bvv = ((const f32x4*)bv)[f0 >> 2];
      #pragma unroll
      for (int m = 0; m < 4; m++){
        const int brow = m*16 + l16;
        uint2 pk;
        pk.x = pk2bf(tanhf_fast(acc[m][nt][0] + bvv[0]),
                     tanhf_fast(acc[m][nt][1] + bvv[1]));
        pk.y = pk2bf(tanhf_fast(acc[m][nt][2] + bvv[2]),
                     tanhf_fast(acc[m][nt][3] + bvv[3]));
        *(uint2*)&dst[brow][f0] = pk;
      }
    }
  };

  // ---- (64x256)x(256x256): wave = 2 n-tiles, all 4 m-tiles ----
  auto gemm256 = [&](const __bf16 (*A)[LDA], const __bf16* __restrict__ Bw,
                     const float* __restrict__ bias, __bf16 (*dst)[LDA], int epi){
    f32x4 acc[4][2];
    #pragma unroll
    for (int m = 0; m < 4; m++){ f32x4 z={0.f,0.f,0.f,0.f}; acc[m][0]=z; acc[m][1]=z; }
    const v8bf* B = (const v8bf*)Bw;
    __builtin_amdgcn_s_setprio(1);
    #pragma unroll
    for (int kk = 0; kk < 8; kk++){
      v8bf a[4];
      #pragma unroll
      for (int m = 0; m < 4; m++)
        a[m] = *(const v8bf*)&A[m*16 + l16][kk*32 + quad*8];
      #pragma unroll
      for (int nt = 0; nt < 2; nt++){
        v8bf bf = B[(kk*16 + wave*2 + nt)*64 + lane];
        #pragma unroll
        for (int m = 0; m < 4; m++)
          acc[m][nt] = __builtin_amdgcn_mfma_f32_16x16x32_bf16(bf, a[m], acc[m][nt], 0,0,0);
      }
    }
    __builtin_amdgcn_s_setprio(0);
    #pragma unroll
    for (int nt = 0; nt < 2; nt++){
      const int f0 = (wave*2 + nt)*16 + quad*4;
      f32x4 bvv = {0.f,0.f,0.f,0.f};
      if (epi == 0) bvv = ((const f32x4*)bias)[f0 >> 2];
      #pragma unroll
      for (int m = 0; m < 4; m++){
        const int brow = m*16 + l16;
        uint2 pk;
        if (epi == 0){
          pk.x = pk2bf(tanhf_fast(acc[m][nt][0] + bvv[0]),
                       tanhf_fast(acc[m][nt][1] + bvv[1]));
          pk.y = pk2bf(tanhf_fast(acc[m][nt][2] + bvv[2]),
                       tanhf_fast(acc[m][nt][3] + bvv[3]));
        } else {
          uint2 old = *(const uint2*)&dst[brow][f0];
          float a0 = bflo(old.x), a1 = bfhi(old.x);
          float c0 = bflo(old.y), c1 = bfhi(old.y);
          pk.x = pk2bf(acc[m][nt][0] * (1.0f - a0*a0),
                       acc[m][nt][1] * (1.0f - a1*a1));
          pk.y = pk2bf(acc[m][nt][2] * (1.0f - c0*c0),
                       acc[m][nt][3] * (1.0f - c1*c1));
        }
        *(uint2*)&dst[brow][f0] = pk;
      }
    }
  };

  // ---- U2 with fused U3 dot: u2 never materialized. Per-lane partial of
  // sum_col tanh(z2+b)*Uw3[col] over the wave's 32 cols, quad-reduced. ----
  auto u2dot = [&](const __bf16 (*A)[LDA], const __bf16* __restrict__ Bw,
                   const float* __restrict__ bias, const float* __restrict__ w3){
    f32x4 acc[4][2];
    #pragma unroll
    for (int m = 0; m < 4; m++){ f32x4 z={0.f,0.f,0.f,0.f}; acc[m][0]=z; acc[m][1]=z; }
    const v8bf* B = (const v8bf*)Bw;
    __builtin_amdgcn_s_setprio(1);
    #pragma unroll
    for (int kk = 0; kk < 8; kk++){
      v8bf a[4];
      #pragma unroll
      for (int m = 0; m < 4; m++)
        a[m] = *(const v8bf*)&A[m*16 + l16][kk*32 + quad*8];
      #pragma unroll
      for (int nt = 0; nt < 2; nt++){
        v8bf bf = B[(kk*16 + wave*2 + nt)*64 + lane];
        #pragma unroll
        for (int m = 0; m < 4; m++)
          acc[m][nt] = __builtin_amdgcn_mfma_f32_16x16x32_bf16(bf, a[m], acc[m][nt], 0,0,0);
      }
    }
    __builtin_amdgcn_s_setprio(0);
    float part[4] = {0.f, 0.f, 0.f, 0.f};
    #pragma unroll
    for (int nt = 0; nt < 2; nt++){
      const int f0 = (wave*2 + nt)*16 + quad*4;
      f32x4 bvv = ((const f32x4*)bias)[f0 >> 2];
      f32x4 w3v = ((const f32x4*)w3)[f0 >> 2];
      #pragma unroll
      for (int m = 0; m < 4; m++)
        #pragma unroll
        for (int r = 0; r < 4; r++)
          part[m] = __builtin_fmaf(tanhf_fast(acc[m][nt][r] + bvv[r]), w3v[r], part[m]);
    }
    #pragma unroll
    for (int m = 0; m < 4; m++){
      part[m] += __shfl_xor(part[m], 16);
      part[m] += __shfl_xor(part[m], 32);
    }
    if (quad == 0){
      #pragma unroll
      for (int m = 0; m < 4; m++)
        s3.r4[wave][m*16 + l16][0] = part[m];
    }
  };

  // ---- N=16 MFMA reduction partial (grad_V): K split across 8 waves ----
  auto mfma_reduce4 = [&](const __bf16 (*A)[LDA], const __bf16* __restrict__ Bw){
    f32x4 acc[4];
    #pragma unroll
    for (int m = 0; m < 4; m++){ f32x4 z={0.f,0.f,0.f,0.f}; acc[m]=z; }
    const v8bf* B = (const v8bf*)Bw;
    v8bf bf = B[wave*64 + lane];           // frag ks = wave (NT=1)
    __builtin_amdgcn_s_setprio(1);
    #pragma unroll
    for (int m = 0; m < 4; m++){
      v8bf a = *(const v8bf*)&A[m*16 + l16][wave*32 + quad*8];
      acc[m] = __builtin_amdgcn_mfma_f32_16x16x32_bf16(bf, a, acc[m], 0,0,0);
    }
    __builtin_amdgcn_s_setprio(0);
    if (quad == 0){
      #pragma unroll
      for (int m = 0; m < 4; m++)
        *(f32x4*)&s3.r4[wave][m*16 + l16][0] = acc[m];
    }
  };

  // ========== phase A: both layer-1s (independent, no barrier between) ====
  layer1m(ws + OFF_LU1, Ub1, b2);          // u1 -> b2
  layer1m(ws + OFF_LV1, Vb1, b1);          // a1 -> b1
  __syncthreads();
  // ========== phase B: U2 + fused U3 dot -> r4 partials ====
  u2dot(b2, ws + OFF_U2T, Ub2, Uw3);
  __syncthreads();
  // ========== phase C: V2 (a2 -> b2); wave 0 finishes u ====
  gemm256(b1, ws + OFF_B2T, Vb2, b2, 0);
  if (tid < RPB){
    float z = Ub3[0];
    #pragma unroll
    for (int w = 0; w < 8; w++) z += s3.r4[w][tid][0];
    float u = tanhf_fast(z) * 20.0f;
    utile[tid] = u;
    out[row0 + tid] = u;
  }
  __syncthreads();

  // ========== phase D: z3 = a2 @ Vw3^T; fused V partials; a3' -> s3.b3 ====
  {
    const int mp = wave >> 2;     // 0..1
    const int nt = wave & 3;      // 0..3
    f32x4 acc[2];
    { f32x4 z={0.f,0.f,0.f,0.f}; acc[0]=z; acc[1]=z; }
    const v8bf* B = (const v8bf*)(ws + OFF_B3T);
    __builtin_amdgcn_s_setprio(1);
    #pragma unroll
    for (int kk = 0; kk < 8; kk++){
      v8bf bf = B[(kk*4 + nt)*64 + lane];
      #pragma unroll
      for (int m2 = 0; m2 < 2; m2++){
        v8bf a = *(const v8bf*)&b2[(mp*2 + m2)*16 + l16][kk*32 + quad*8];
        acc[m2] = __builtin_amdgcn_mfma_f32_16x16x32_bf16(bf, a, acc[m2], 0,0,0);
      }
    }
    __builtin_amdgcn_s_setprio(0);
    const int f0 = nt*16 + quad*4;
    f32x4 bvv = ((const f32x4*)Vb3)[f0 >> 2];
    #pragma unroll
    for (int m2 = 0; m2 < 2; m2++){
      const int brow = (mp*2 + m2)*16 + l16;
      float t0 = tanhf_fast(acc[m2][0] + bvv[0]);
      float t1 = tanhf_fast(acc[m2][1] + bvv[1]);
      float t2 = tanhf_fast(acc[m2][2] + bvv[2]);
      float t3 = tanhf_fast(acc[m2][3] + bvv[3]);
      float s0 = t0*t0, s1 = t1*t1, s2 = t2*t2, s3q = t3*t3;
      float sq = (s0 + s1) + (s2 + s3q);
      sq += __shfl_xor(sq, 16);
      sq += __shfl_xor(sq, 32);
      if (quad == 0) red[brow][nt] = sq;
      uint2 pk;
      pk.x = pk2bf(t0*(1.0f - s0), t1*(1.0f - s1));
      pk.y = pk2bf(t2*(1.0f - s2), t3*(1.0f - s3q));
      *(uint2*)&s3.b3[brow][f0] = pk;
    }
  }
  __syncthreads();

  // ========== phase E: t3 = a3' @ Vw3; t2' = t3*(1-a2^2) in-place; emit V ==
  {
    f32x4 acc[4][2];
    #pragma unroll
    for (int m = 0; m < 4; m++){ f32x4 z={0.f,0.f,0.f,0.f}; acc[m][0]=z; acc[m][1]=z; }
    const v8bf* B = (const v8bf*)(ws + OFF_B3);
    __builtin_amdgcn_s_setprio(1);
    #pragma unroll
    for (int kk = 0; kk < 2; kk++){
      v8bf a[4];
      #pragma unroll
      for (int m = 0; m < 4; m++)
        a[m] = *(const v8bf*)&s3.b3[m*16 + l16][kk*32 + quad*8];
      #pragma unroll
      for (int nt = 0; nt < 2; nt++){
        v8bf bf = B[(kk*16 + wave*2 + nt)*64 + lane];
        #pragma unroll
        for (int m = 0; m < 4; m++)
          acc[m][nt] = __builtin_amdgcn_mfma_f32_16x16x32_bf16(bf, a[m], acc[m][nt], 0,0,0);
      }
    }
    __builtin_amdgcn_s_setprio(0);
    #pragma unroll
    for (int nt = 0; nt < 2; nt++){
      const int f0 = (wave*2 + nt)*16 + quad*4;
      #pragma unroll
      for (int m = 0; m < 4; m++){
        const int brow = m*16 + l16;
        uint2 old = *(const uint2*)&b2[brow][f0];
        float a0 = bflo(old.x), a1 = bfhi(old.x);
        float c0 = bflo(old.y), c1 = bfhi(old.y);
        uint2 pk;
        pk.x = pk2bf(acc[m][nt][0] * (1.0f - a0*a0),
                     acc[m][nt][1] * (1.0f - a1*a1));
        pk.y = pk2bf(acc[m][nt][2] * (1.0f - c0*c0),
                     acc[m][nt][3] * (1.0f - c1*c1));
        *(uint2*)&b2[brow][f0] = pk;
      }
    }
    if (tid < RPB)
      out[BSZ + row0 + tid] = 0.5f * (red[tid][0] + red[tid][1] + red[tid][2] + red[tid][3]);
  }
  __syncthreads();

  // ========== phase F: s2' = (t2'@Vw2)*(1-a1^2) -> b1 ====
  gemm256(b2, ws + OFF_B2, nullptr, b1, 1);
  __syncthreads();
  // ========== phase G: grad_V partials -> r4 (b3 dead) ====
  mfma_reduce4(b1, ws + OFF_GV);
  __syncthreads();
  // ========== phase H: cross-wave sum ====
  if (tid < 256){
    int b = tid >> 2, k2 = tid & 3;
    float s = 0.f;
    #pragma unroll
    for (int w = 0; w < 8; w++) s += s3.r4[w][b][k2];
    red[b][k2] = s;
  }
  __syncthreads();

  // ========== tail: dynamics + Vdot ====
  if (tid < RPB){
    float4 xv = ((const float4*)x)[row0 + tid];
    float th = xv.y, vv = xv.z, om = xv.w;
    float c, s;
    __sincosf(th, &s, &c);
    float rdc  = __builtin_amdgcn_rcpf(c - 24.7f);
    float rdc2 = __builtin_amdgcn_rcpf(c*c - 24.7f);
    float f2v = (c*(9.8f*s + 11.5f*vv) + 68.4f*vv - 1.2f*om*om*s) * rdc;
    float f3v = (-58.8f*vv*c - 243.5f*vv - s*(208.3f + om*om*c)) * rdc2;
    float g2v = (-1.8f*c - 10.9f) * rdc;
    float g3v = (9.3f*c + 38.6f) * rdc2;
    f32x4 rv = *(const f32x4*)&red[tid][0];
    float Lf = rv[0]*vv + rv[1]*om + rv[2]*f2v + rv[3]*f3v;
    float Lg = rv[2]*g2v + rv[3]*g3v;
    out[2*BSZ + row0 + tid] = Lf + Lg * utile[tid];
  }
}

extern "C" void kernel_launch(void* const* d_in, const int* in_sizes, int n_in,
                              void* d_out, int out_size, void* d_ws, size_t ws_size,
                              hipStream_t stream) {
  const float* x   = (const float*)d_in[0];
  const float* Vw1 = (const float*)d_in[1];
  const float* Vb1 = (const float*)d_in[2];
  const float* Vw2 = (const float*)d_in[3];
  const float* Vb2 = (const float*)d_in[4];
  const float* Vw3 = (const float*)d_in[5];
  const float* Vb3 = (const float*)d_in[6];
  const float* Uw1 = (const float*)d_in[7];
  const float* Ub1 = (const float*)d_in[8];
  const float* Uw2 = (const float*)d_in[9];
  const float* Ub2 = (const float*)d_in[10];
  const float* Uw3 = (const float*)d_in[11];
  const float* Ub3 = (const float*)d_in[12];
  __bf16* ws = (__bf16*)d_ws;
  float* out = (float*)d_out;

  hipLaunchKernelGGL(prep_weights, dim3((WS_ELEMS + 255) / 256), dim3(256), 0, stream,
                     Vw2, Uw2, Vw3, Vw1, Uw1, Uw3, ws);
  hipLaunchKernelGGL(fused_clf, dim3(BSZ / RPB), dim3(NTHREADS), 0, stream,
                     x, Vb1, Vb2, Vb3, Ub1, Ub2, Ub3, Uw3, ws, out);
}